// Round 5
// baseline (429.487 us; speedup 1.0000x reference)
//
#include <hip/hip_runtime.h>
#include <math.h>

#define CH 4096        // edges per partition block
#define NBUK_MAX 256   // max buckets (N <= 131072)
#define MAXB 12288     // max edges per bucket staged in LDS (48 KB)

// ---------------- P1a: per-block bucket histograms (dst-bucket and src-bucket) ----------------
__global__ __launch_bounds__(256) void p1a_kernel(const int* __restrict__ src, const int* __restrict__ dst,
                                                  int* __restrict__ mat, int E, int B1, int nbuk) {
    __shared__ int hd[NBUK_MAX], hs[NBUK_MAX];
    const int t = threadIdx.x;
    if (t < nbuk) { hd[t] = 0; hs[t] = 0; }
    __syncthreads();
    const int base = blockIdx.x * CH;
    const int cnt = min(CH, E - base);
    for (int k = t; k < cnt; k += 256) {
        int d = dst[base + k];
        int s = src[base + k];
        atomicAdd(&hd[d >> 9], 1);
        atomicAdd(&hs[s >> 9], 1);
    }
    __syncthreads();
    if (t < nbuk) {
        mat[t * B1 + blockIdx.x] = hd[t];
        mat[(nbuk + t) * B1 + blockIdx.x] = hs[t];
    }
}

// ---------------- 3-phase exclusive scan ----------------
__global__ __launch_bounds__(256) void scan1_kernel(const int* __restrict__ cnt,
                                                    int* __restrict__ seg,
                                                    int* __restrict__ bsums, int N) {
    __shared__ int tsum[256];
    const int t = threadIdx.x;
    const int base = blockIdx.x * 1024 + t * 4;
    int v0 = (base + 0 < N) ? cnt[base + 0] : 0;
    int v1 = (base + 1 < N) ? cnt[base + 1] : 0;
    int v2 = (base + 2 < N) ? cnt[base + 2] : 0;
    int v3 = (base + 3 < N) ? cnt[base + 3] : 0;
    tsum[t] = v0 + v1 + v2 + v3;
    __syncthreads();
    for (int off = 1; off < 256; off <<= 1) {
        int x = (t >= off) ? tsum[t - off] : 0;
        __syncthreads();
        if (t >= off) tsum[t] += x;
        __syncthreads();
    }
    int run = (t > 0) ? tsum[t - 1] : 0;
    if (base + 0 < N) seg[base + 0] = run; run += v0;
    if (base + 1 < N) seg[base + 1] = run; run += v1;
    if (base + 2 < N) seg[base + 2] = run; run += v2;
    if (base + 3 < N) seg[base + 3] = run;
    if (t == 255) bsums[blockIdx.x] = tsum[255];
}

__global__ void scan2_kernel(int* __restrict__ bsums, int* __restrict__ seg, int N, int G) {
    __shared__ int s[256];
    int t = threadIdx.x;
    if (t < G) s[t] = bsums[t];
    __syncthreads();
    if (t == 0) {
        int run = 0;
        for (int i = 0; i < G; ++i) { int v = s[i]; s[i] = run; run += v; }
        seg[N] = run;
    }
    __syncthreads();
    if (t < G) bsums[t] = s[t];
}

__global__ __launch_bounds__(256) void scan3_kernel(int* __restrict__ seg,
                                                    const int* __restrict__ bsums, int N) {
    int add = bsums[blockIdx.x];
    int base = blockIdx.x * 1024 + threadIdx.x * 4;
#pragma unroll
    for (int i = 0; i < 4; ++i) {
        int idx = base + i;
        if (idx < N) seg[idx] += add;
    }
}

// ---------------- P1c: LDS-staged partition scatter ----------------
__global__ __launch_bounds__(256) void p1c_kernel(const int* __restrict__ src, const int* __restrict__ dst,
                                                  const int* __restrict__ scan,
                                                  int* __restrict__ pd, int* __restrict__ psqs,
                                                  int E, int B1, int nbuk) {
    __shared__ int hd[NBUK_MAX], hs[NBUK_MAX];
    __shared__ int curD[NBUK_MAX], curS[NBUK_MAX];
    __shared__ int baseD[NBUK_MAX], baseS[NBUK_MAX];
    __shared__ int stD_d[CH];
    __shared__ int stD_s[CH];
    __shared__ int stS_s[CH];
    const int t = threadIdx.x;
    if (t < nbuk) { hd[t] = 0; hs[t] = 0; }
    __syncthreads();
    const int base = blockIdx.x * CH;
    const int cnt = min(CH, E - base);
    int dl[CH / 256], sl[CH / 256];
#pragma unroll
    for (int k = 0; k < CH / 256; ++k) {
        int i = t + k * 256;
        if (i < cnt) {
            dl[k] = dst[base + i];
            sl[k] = src[base + i];
            atomicAdd(&hd[dl[k] >> 9], 1);
            atomicAdd(&hs[sl[k] >> 9], 1);
        }
    }
    __syncthreads();
    for (int off = 1; off < nbuk; off <<= 1) {
        int v0 = (t >= off && t < nbuk) ? hd[t - off] : 0;
        int w0 = (t >= off && t < nbuk) ? hs[t - off] : 0;
        __syncthreads();
        if (t < nbuk) { hd[t] += v0; hs[t] += w0; }
        __syncthreads();
    }
    if (t < nbuk) {
        int excD = t ? hd[t - 1] : 0;
        int excS = t ? hs[t - 1] : 0;
        curD[t] = excD;
        curS[t] = excS;
        baseD[t] = scan[t * B1 + blockIdx.x] - excD;
        baseS[t] = scan[(nbuk + t) * B1 + blockIdx.x] - excS;
    }
    __syncthreads();
#pragma unroll
    for (int k = 0; k < CH / 256; ++k) {
        int i = t + k * 256;
        if (i < cnt) {
            int j = dl[k] >> 9;
            int p = atomicAdd(&curD[j], 1);
            stD_d[p] = dl[k];
            stD_s[p] = sl[k];
            int jq = sl[k] >> 9;
            int q = atomicAdd(&curS[jq], 1);
            stS_s[q] = sl[k];
        }
    }
    __syncthreads();
    for (int i = t; i < cnt; i += 256) {
        int lo = 0, hi = nbuk - 1;
        while (lo < hi) { int mid = (lo + hi) >> 1; if (hd[mid] > i) hi = mid; else lo = mid + 1; }
        int gd = baseD[lo] + i;
        pd[gd] = stD_d[i];
        psqs[gd] = stD_s[i];
        int lo2 = 0, hi2 = nbuk - 1;
        while (lo2 < hi2) { int mid = (lo2 + hi2) >> 1; if (hs[mid] > i) hi2 = mid; else lo2 = mid + 1; }
        psqs[baseS[lo2] + i] = stS_s[i];
    }
}

// ---------------- P2: per-bucket local sort -> esrc (coalesced), seg, norm_dst ----------------
__global__ __launch_bounds__(256) void p2_kernel(const int* __restrict__ pd, const int* __restrict__ ps,
                                                 const int* __restrict__ scan,
                                                 int* __restrict__ esrc, int* __restrict__ seg,
                                                 float* __restrict__ norm_dst,
                                                 int N, int E, int B1) {
    __shared__ int h[512];
    __shared__ int cur[512];
    __shared__ int stage[MAXB];
    const int t = threadIdx.x;
    const int b = blockIdx.x;
    h[t] = 0; h[t + 256] = 0;
    __syncthreads();
    const int bb0 = scan[b * B1];
    const int bb1 = scan[(b + 1) * B1];
    for (int i = bb0 + t; i < bb1; i += 256) atomicAdd(&h[pd[i] & 511], 1);
    __syncthreads();
    for (int off = 1; off < 512; off <<= 1) {
        int v0 = (t >= off) ? h[t - off] : 0;
        int v1 = (t + 256 >= off) ? h[t + 256 - off] : 0;
        __syncthreads();
        h[t] += v0;
        h[t + 256] += v1;
        __syncthreads();
    }
#pragma unroll
    for (int r = 0; r < 2; ++r) {
        int j = t + r * 256;
        int exc = j ? h[j - 1] : 0;
        cur[j] = exc;
        int n = (b << 9) + j;
        if (n < N) {
            seg[n] = bb0 + exc;
            norm_dst[n] = rsqrtf(fmaxf((float)(h[j] - exc), 1.0f));
        }
    }
    if (b == 0 && t == 0) seg[N] = E;
    __syncthreads();
    const int cnt = bb1 - bb0;
    for (int i = bb0 + t; i < bb1; i += 256) {
        int j = pd[i] & 511;
        int p = atomicAdd(&cur[j], 1);
        int s = ps[i];
        if (p < MAXB) stage[p] = s; else esrc[bb0 + p] = s;
    }
    __syncthreads();
    for (int i = t; i < cnt && i < MAXB; i += 256) esrc[bb0 + i] = stage[i];
}

// ---------------- S2: per-bucket src histogram -> norm_src ----------------
__global__ __launch_bounds__(256) void s2_kernel(const int* __restrict__ psqs, const int* __restrict__ scan,
                                                 float* __restrict__ norm_src, int N, int B1, int nbuk) {
    __shared__ int h[512];
    const int t = threadIdx.x;
    const int b = blockIdx.x;
    h[t] = 0; h[t + 256] = 0;
    __syncthreads();
    const int sb0 = scan[(nbuk + b) * B1];
    const int sb1 = scan[(nbuk + b + 1) * B1];
    for (int i = sb0 + t; i < sb1; i += 256) atomicAdd(&h[psqs[i] & 511], 1);
    __syncthreads();
#pragma unroll
    for (int r = 0; r < 2; ++r) {
        int j = t + r * 256;
        int n = (b << 9) + j;
        if (n < N) norm_src[n] = rsqrtf(fmaxf((float)h[j], 1.0f));
    }
}

// ---------------- X = (H @ W) * norm_row ----------------
// 256 nodes x 64 cols per block; BK=16; 8x8 register blocking.
// sA stored [k][node] (stride 260): inner-loop A-reads are ds_read_b128 over
// consecutive nodes (2-way bank aliasing = free); sB reads 8-way broadcast.
// Staging transposes A via conflict-free scalar LDS writes. 0.25 LDS
// floats/FMA -> VALU-bound (~10 us floor for K=128).
template<int K>
__global__ __launch_bounds__(256) void gemm_norm(const float* __restrict__ H,
                                                 const float* __restrict__ W,
                                                 const float* __restrict__ norm,
                                                 float* __restrict__ X, int N) {
    constexpr int BK = 16;
    constexpr int NCH = K / BK;
    constexpr int LDA = 260;
    __shared__ __align__(16) float sA[BK * LDA];
    __shared__ __align__(16) float sB[BK * 64];
    const int tid = threadIdx.x;
    const int n0 = blockIdx.x * 256;

    const int an = tid;               // staging node (column of sA)
    const int bk = tid >> 4;          // staging k for sB
    const int bc = (tid & 15) * 4;    // staging col for sB

    const int tx = tid & 7;           // cols 8tx .. 8tx+7
    const int ty = tid >> 3;          // nodes 8ty .. 8ty+7

    const float4 z4 = {0.0f, 0.0f, 0.0f, 0.0f};
    const float* Hrow = H + (size_t)(n0 + an) * K;
    const bool arow_ok = (n0 + an) < N;

    float4 a_pf[4];
    float4 b_pf;
#pragma unroll
    for (int q = 0; q < 4; ++q)
        a_pf[q] = arow_ok ? *(const float4*)&Hrow[q * 4] : z4;
    b_pf = *(const float4*)&W[(size_t)bk * 64 + bc];

    float acc[8][8];
#pragma unroll
    for (int i = 0; i < 8; ++i)
#pragma unroll
        for (int j = 0; j < 8; ++j) acc[i][j] = 0.0f;

    for (int c = 0; c < NCH; ++c) {
        __syncthreads();
#pragma unroll
        for (int q = 0; q < 4; ++q) {
            sA[(q * 4 + 0) * LDA + an] = a_pf[q].x;
            sA[(q * 4 + 1) * LDA + an] = a_pf[q].y;
            sA[(q * 4 + 2) * LDA + an] = a_pf[q].z;
            sA[(q * 4 + 3) * LDA + an] = a_pf[q].w;
        }
        *(float4*)&sB[bk * 64 + bc] = b_pf;
        __syncthreads();
        if (c + 1 < NCH) {
            const int k0 = (c + 1) * BK;
#pragma unroll
            for (int q = 0; q < 4; ++q)
                a_pf[q] = arow_ok ? *(const float4*)&Hrow[k0 + q * 4] : z4;
            b_pf = *(const float4*)&W[(size_t)(k0 + bk) * 64 + bc];
        }
#pragma unroll
        for (int k = 0; k < BK; ++k) {
            const float4 aA = *(const float4*)&sA[k * LDA + 8 * ty];
            const float4 aB = *(const float4*)&sA[k * LDA + 8 * ty + 4];
            const float4 bA = *(const float4*)&sB[k * 64 + 8 * tx];
            const float4 bB = *(const float4*)&sB[k * 64 + 8 * tx + 4];
            const float a[8] = {aA.x, aA.y, aA.z, aA.w, aB.x, aB.y, aB.z, aB.w};
            const float b[8] = {bA.x, bA.y, bA.z, bA.w, bB.x, bB.y, bB.z, bB.w};
#pragma unroll
            for (int i = 0; i < 8; ++i)
#pragma unroll
                for (int j = 0; j < 8; ++j)
                    acc[i][j] += a[i] * b[j];
        }
    }

#pragma unroll
    for (int i = 0; i < 8; ++i) {
        const int n = n0 + 8 * ty + i;
        if (n < N) {
            const float s = norm[n];
            float4 o0, o1;
            o0.x = acc[i][0] * s; o0.y = acc[i][1] * s; o0.z = acc[i][2] * s; o0.w = acc[i][3] * s;
            o1.x = acc[i][4] * s; o1.y = acc[i][5] * s; o1.z = acc[i][6] * s; o1.w = acc[i][7] * s;
            *(float4*)&X[(size_t)n * 64 + 8 * tx] = o0;
            *(float4*)&X[(size_t)n * 64 + 8 * tx + 4] = o1;
        }
    }
}

// ---------------- segment sum over CSR + fused epilogue ----------------
template<bool ELU>
__global__ __launch_bounds__(256) void segsum_kernel(const float* __restrict__ X,
                                                     const int* __restrict__ esrc,
                                                     const int* __restrict__ seg,
                                                     const float* __restrict__ norm_dst,
                                                     const float* __restrict__ b,
                                                     float* __restrict__ out, int N) {
    const int node = blockIdx.x * 4 + (threadIdx.x >> 6);
    const int lane = threadIdx.x & 63;
    if (node >= N) return;
    const int s0 = seg[node];
    const int s1 = seg[node + 1];
    float acc = 0.0f;
    int e = s0;
    for (; e + 8 <= s1; e += 8) {
        int a0 = esrc[e + 0]; int a1 = esrc[e + 1];
        int a2 = esrc[e + 2]; int a3 = esrc[e + 3];
        int a4 = esrc[e + 4]; int a5 = esrc[e + 5];
        int a6 = esrc[e + 6]; int a7 = esrc[e + 7];
        float v0 = X[(size_t)a0 * 64 + lane];
        float v1 = X[(size_t)a1 * 64 + lane];
        float v2 = X[(size_t)a2 * 64 + lane];
        float v3 = X[(size_t)a3 * 64 + lane];
        float v4 = X[(size_t)a4 * 64 + lane];
        float v5 = X[(size_t)a5 * 64 + lane];
        float v6 = X[(size_t)a6 * 64 + lane];
        float v7 = X[(size_t)a7 * 64 + lane];
        acc += v0; acc += v1; acc += v2; acc += v3;
        acc += v4; acc += v5; acc += v6; acc += v7;
    }
    for (; e < s1; ++e) acc += X[(size_t)esrc[e] * 64 + lane];
    float r = acc * norm_dst[node] + b[lane];
    if (ELU) r = (r > 0.0f) ? r : expm1f(r);
    out[(size_t)node * 64 + lane] = r;
}

extern "C" void kernel_launch(void* const* d_in, const int* in_sizes, int n_in,
                              void* d_out, int out_size, void* d_ws, size_t ws_size,
                              hipStream_t stream) {
    const float* h   = (const float*)d_in[0];
    const int*   src = (const int*)d_in[1];
    const int*   dst = (const int*)d_in[2];
    const float* W1  = (const float*)d_in[3];
    const float* b1  = (const float*)d_in[4];
    const float* W2  = (const float*)d_in[5];
    const float* b2  = (const float*)d_in[6];
    float* out = (float*)d_out;

    const int N = in_sizes[0] / 128;       // 100000
    const int E = in_sizes[1];             // 1600000
    const int nbuk = (N + 511) >> 9;       // 196
    const int B1 = (E + CH - 1) / CH;      // 391
    const int M = 2 * nbuk * B1;

    int* iw = (int*)d_ws;
    int* mat   = iw;
    int* scanb = mat + M;
    int* bsums = scanb + M + 4;
    int* pd    = bsums + 256;
    int* psqs  = pd + (size_t)E;
    int* esrc  = psqs + 2 * (size_t)E;
    int* seg   = esrc + (size_t)E;
    float* fw       = (float*)(seg + (size_t)N + 4);
    float* norm_src = fw;
    float* norm_dst = fw + (size_t)N;
    float* X        = fw + 2 * (size_t)N;
    float* H1       = X + 64 * (size_t)N;

    // ---- CSR build ----
    p1a_kernel<<<B1, 256, 0, stream>>>(src, dst, mat, E, B1, nbuk);
    const int G = (M + 1023) / 1024;
    scan1_kernel<<<G, 256, 0, stream>>>(mat, scanb, bsums, M);
    scan2_kernel<<<1, 256, 0, stream>>>(bsums, scanb, M, G);
    scan3_kernel<<<G, 256, 0, stream>>>(scanb, bsums, M);
    p1c_kernel<<<B1, 256, 0, stream>>>(src, dst, scanb, pd, psqs, E, B1, nbuk);
    p2_kernel<<<nbuk, 256, 0, stream>>>(pd, psqs, scanb, esrc, seg, norm_dst, N, E, B1);
    s2_kernel<<<nbuk, 256, 0, stream>>>(psqs, scanb, norm_src, N, B1, nbuk);

    // ---- layer 1 ----
    gemm_norm<128><<<(N + 255) / 256, 256, 0, stream>>>(h, W1, norm_src, X, N);
    segsum_kernel<true><<<(N + 3) / 4, 256, 0, stream>>>(X, esrc, seg, norm_dst, b1, H1, N);

    // ---- layer 2 ----
    gemm_norm<64><<<(N + 255) / 256, 256, 0, stream>>>(H1, W2, norm_src, X, N);
    segsum_kernel<false><<<(N + 3) / 4, 256, 0, stream>>>(X, esrc, seg, norm_dst, b2, out, N);
}